// Round 2
// baseline (117.713 us; speedup 1.0000x reference)
//
#include <hip/hip_runtime.h>
#include <math.h>

// Workspace float offsets (ws)
#define FVC_OFF   0          // 128 * 1024
#define PHIQ_OFF  131072     // 128 * 1024
#define PHIK_OFF  262144     // 128 * 1024
#define OUT_KX_OFF 4194304   // kx location in d_out (after 4*32*256*128 floats)

#define TWOPI_128 0.049087385212340517f
#define OUT_SCALE 6.103515625e-05f   // 1/16384

// ---------------------------------------------------------------------------
// Fused K1+K2: one block per image (256 images), 512 threads.
// Phase 1: row DFT (w -> 16 v modes) for all 128 h rows, G kept in LDS.
//          4 passes of 32 rows, staging software-pipelined (prefetch regs).
// Phase 2: column DFT (h -> u in {0..15,112..127}) + weights/phi/conv,
//          identical math to the old modes_kernel.
// Also zero-fills the output top half (8192 floats per block) to offload K3.
// ---------------------------------------------------------------------------
__global__ __launch_bounds__(512) void dft_modes_kernel(
    const float* __restrict__ z,
    const float* __restrict__ qw1r, const float* __restrict__ qw1i,
    const float* __restrict__ qw2r, const float* __restrict__ qw2i,
    const float* __restrict__ kw1r, const float* __restrict__ kw1i,
    const float* __restrict__ kw2r, const float* __restrict__ kw2i,
    const float* __restrict__ icl,  const float* __restrict__ ker,
    float* __restrict__ ws, float* __restrict__ out)
{
    __shared__ float2 tw[128];
    __shared__ float rows[32 * 132];     // 32 staged input rows (pad 132)
    __shared__ float Gs[16 * 260];       // G[v][h] complex, stride 260 (pad)
    __shared__ float f0r[64], f0i[64];

    const int tid = threadIdx.x;
    const int img = blockIdx.x;
    const int bt  = img & 127;
    const int isY = img >> 7;

    // ---- zero-fill output top half: rows [isY*64, isY*64+64) of image bt ----
    {
        const float4 z4 = make_float4(0.f, 0.f, 0.f, 0.f);
        float* zb = out + (size_t)bt * 32768 + (size_t)isY * 8192;
        #pragma unroll
        for (int k = 0; k < 4; ++k)
            *(float4*)(zb + (size_t)(tid + k * 512) * 4) = z4;
    }

    if (tid < 128) {
        float s, c;
        sincosf((float)tid * TWOPI_128, &s, &c);
        tw[tid] = make_float2(c, s);
    }

    const float* xim = z + (size_t)bt * 32768 + (size_t)isY * 16384;
    const int half = tid >> 8;          // which 16-row sub-chunk this thread computes
    const int t8   = tid & 255;
    const int v1   = t8 & 15;           // row-DFT output mode
    const int hl   = t8 >> 4;           // row within 16-row sub-chunk

    // prefetch pass 0 staging (2 float4 per thread = 32 rows)
    float4 a0 = *(const float4*)(xim + (size_t)tid * 4);
    float4 a1 = *(const float4*)(xim + (size_t)(tid + 512) * 4);

    for (int p = 0; p < 4; ++p) {
        __syncthreads();   // previous pass done reading rows[]
        {
            const int q0 = tid, q1 = tid + 512;
            *(float4*)(rows + (q0 >> 5) * 132 + (q0 & 31) * 4) = a0;
            *(float4*)(rows + (q1 >> 5) * 132 + (q1 & 31) * 4) = a1;
        }
        if (p < 3) {   // issue next pass's loads now; they complete under compute
            const float* nx = xim + (size_t)(p + 1) * 4096;
            a0 = *(const float4*)(nx + (size_t)tid * 4);
            a1 = *(const float4*)(nx + (size_t)(tid + 512) * 4);
        }
        __syncthreads();   // rows[] ready

        // ---- row DFT: radix-4 split, register-rotated twiddles (K1 math) ----
        const float2 stp = tw[(4 * v1) & 127];
        float cc = 1.f, ss = 0.f;
        float sr0 = 0.f, si0 = 0.f, sr1 = 0.f, si1 = 0.f;
        float sr2 = 0.f, si2 = 0.f, sr3 = 0.f, si3 = 0.f;
        const float4* rp = (const float4*)(rows + (half * 16 + hl) * 132);
        #pragma unroll 8
        for (int m = 0; m < 32; ++m) {
            float4 x4 = rp[m];
            sr0 = fmaf(x4.x, cc, sr0); si0 = fmaf(x4.x, ss, si0);
            sr1 = fmaf(x4.y, cc, sr1); si1 = fmaf(x4.y, ss, si1);
            sr2 = fmaf(x4.z, cc, sr2); si2 = fmaf(x4.z, ss, si2);
            sr3 = fmaf(x4.w, cc, sr3); si3 = fmaf(x4.w, ss, si3);
            float t0 = fmaf(cc, stp.x, -(ss * stp.y));
            float t1 = fmaf(cc, stp.y,  (ss * stp.x));
            cc = t0; ss = t1;
        }
        float2 w1 = tw[v1];
        float2 w2 = tw[(2 * v1) & 127];
        float2 w3 = tw[(3 * v1) & 127];
        float gr = sr0 + sr1 * w1.x - si1 * w1.y + sr2 * w2.x - si2 * w2.y + sr3 * w3.x - si3 * w3.y;
        float gi = -(si0 + sr1 * w1.y + si1 * w1.x + sr2 * w2.y + si2 * w2.x + sr3 * w3.y + si3 * w3.x);

        const int h = (2 * p + half) * 16 + hl;
        *(float2*)(Gs + v1 * 260 + h * 2) = make_float2(gr, gi);
    }
    __syncthreads();   // Gs complete

    // ---- column DFT + epilogue (old modes_kernel math) ----
    const int uu = tid & 31;
    const int v  = tid >> 5;            // 0..15
    const int u  = (uu < 16) ? uu : uu + 96;

    const float2 stp2 = tw[(4 * u) & 127];
    float cc = 1.f, ss = 0.f;
    float sr[4] = {0.f, 0.f, 0.f, 0.f}, si[4] = {0.f, 0.f, 0.f, 0.f};
    const float4* gp = (const float4*)(Gs + v * 260);
    #pragma unroll 8
    for (int m = 0; m < 32; ++m) {
        float4 ga = gp[2 * m];
        float4 gb = gp[2 * m + 1];
        sr[0] = fmaf(ga.x, cc, fmaf(ga.y,  ss, sr[0]));
        si[0] = fmaf(ga.y, cc, fmaf(-ga.x, ss, si[0]));
        sr[1] = fmaf(ga.z, cc, fmaf(ga.w,  ss, sr[1]));
        si[1] = fmaf(ga.w, cc, fmaf(-ga.z, ss, si[1]));
        sr[2] = fmaf(gb.x, cc, fmaf(gb.y,  ss, sr[2]));
        si[2] = fmaf(gb.y, cc, fmaf(-gb.x, ss, si[2]));
        sr[3] = fmaf(gb.z, cc, fmaf(gb.w,  ss, sr[3]));
        si[3] = fmaf(gb.w, cc, fmaf(-gb.z, ss, si[3]));
        float t0 = fmaf(cc, stp2.x, -(ss * stp2.y));
        float t1 = fmaf(cc, stp2.y,  (ss * stp2.x));
        cc = t0; ss = t1;
    }
    float mr = sr[0], mi_ = si[0];
    #pragma unroll
    for (int j = 1; j < 4; ++j) {
        float2 wj = tw[(u * j) & 127];
        mr  += sr[j] * wj.x + si[j] * wj.y;
        mi_ += si[j] * wj.x - sr[j] * wj.y;
    }

    const int wi = (uu & 15) * 16 + v;

    if (!isY) {
        float a, bi_;
        if (uu < 16) { a = qw1r[wi]; bi_ = qw1i[wi]; }
        else         { a = qw2r[wi]; bi_ = qw2i[wi]; }
        float fqr = mr * a - mi_ * bi_;
        float fqi = mr * bi_ + mi_ * a;
        if (uu < 16) { a = kw1r[wi]; bi_ = kw1i[wi]; }
        else         { a = kw2r[wi]; bi_ = kw2i[wi]; }
        float fkr = mr * a - mi_ * bi_;
        float fki = mr * bi_ + mi_ * a;

        float* PQ = ws + PHIQ_OFF + (size_t)bt * 1024;
        float* PK = ws + PHIK_OFF + (size_t)bt * 1024;
        const float c2 = 0.011048543456039806f;  // sqrt(2)/128
        if (v >= 1) {
            int o = ((v - 1) * 32 + uu) * 2;
            *(float2*)(PQ + o) = make_float2(c2 * fqr, c2 * fqi);
            *(float2*)(PK + o) = make_float2(c2 * fkr, c2 * fki);
        } else {
            f0r[uu]      = fqr; f0i[uu]      = fqi;
            f0r[32 + uu] = fkr; f0i[32 + uu] = fki;
        }
        __syncthreads();
        const float c1n = 0.0078125f;            // 1/128
        if (tid == 0) {
            PQ[960] = c1n * f0r[0];
            PK[960] = c1n * f0r[32];
        } else if (tid <= 15) {
            int uf = tid;
            float hr = 0.5f * (f0r[uf] + f0r[32 - uf]);
            float hi = 0.5f * (f0i[uf] - f0i[32 - uf]);
            int o = 961 + (uf - 1) * 2;
            PQ[o] = c2 * hr; PQ[o + 1] = c2 * hi;
            hr = 0.5f * (f0r[32 + uf] + f0r[32 + (32 - uf)]);
            hi = 0.5f * (f0i[32 + uf] - f0i[32 + (32 - uf)]);
            PK[o] = c2 * hr; PK[o + 1] = c2 * hi;
        } else if (tid == 16) {
            PQ[991] = c2 * 0.5f * f0r[16]; PQ[992] = -c2 * 0.5f * f0i[16];
            PK[991] = c2 * 0.5f * f0r[48]; PK[992] = -c2 * 0.5f * f0i[48];
        } else if (tid < 48) {
            PQ[993 + (tid - 17)] = 0.f;
            PK[993 + (tid - 17)] = 0.f;
        }
    } else {
        float s = icl[0];
        float khr = 0.f, khi = 0.f;
        #pragma unroll
        for (int a2 = 0; a2 < 5; ++a2) {
            #pragma unroll
            for (int c3 = 0; c3 < 5; ++c3) {
                float kv = ker[a2 * 5 + c3];
                float2 e = tw[(u * (a2 - 2) + v * (c3 - 2)) & 127];
                khr = fmaf(kv, e.x, khr);
                khi = fmaf(kv, e.y, khi);
            }
        }
        const int slot = uu * 16 + v;
        float* FV = ws + FVC_OFF + (size_t)bt * 1024;
        *(float2*)(FV + slot * 2) =
            make_float2(s * (mr * khr - mi_ * khi), s * (mr * khi + mi_ * khr));
    }
}

// ---------------------------------------------------------------------------
// K2: per-(b,q,quarter): kx column, mix, inverse transform 32 rows.
// grid 512; block 256. (zeros phase moved into dft_modes_kernel)
// ---------------------------------------------------------------------------
__global__ __launch_bounds__(256) void dist_mix_inv_kernel(
    const float* __restrict__ ws, float* __restrict__ out)
{
    __shared__ float2 tw[128];
    __shared__ float kxs[32];
    __shared__ float fmP[32 * 36];   // slot(u,v) -> u*36 + v*2 (r,i interleaved)
    __shared__ float Az[32 * 36];    // row l   -> l*36 + v*2 (r,i interleaved)

    const int tid     = threadIdx.x;
    const int b       = blockIdx.x >> 7;
    const int rest    = blockIdx.x & 127;
    const int q       = rest >> 2;
    const int quarter = rest & 3;
    const size_t obase = (size_t)(b * 32 + q) * 32768;

    if (tid < 128) {
        float s, c;
        sincosf((float)tid * TWOPI_128, &s, &c);
        tw[tid] = make_float2(c, s);
    }

    // ---- dist: kx[b,t,q] for t=0..31 ----
    {
        const int t = tid >> 3, seg = tid & 7;
        const float4* qp = (const float4*)(ws + PHIQ_OFF + (size_t)(b * 32 + t) * 1024) + seg * 32;
        const float4* kp = (const float4*)(ws + PHIK_OFF + (size_t)(b * 32 + q) * 1024) + seg * 32;
        float acc = 0.f;
        #pragma unroll 8
        for (int d = 0; d < 32; ++d) {
            float4 qv = qp[d], kv = kp[d];
            float d0 = qv.x - kv.x, d1 = qv.y - kv.y;
            float d2 = qv.z - kv.z, d3 = qv.w - kv.w;
            acc = fmaf(d0, d0, acc); acc = fmaf(d1, d1, acc);
            acc = fmaf(d2, d2, acc); acc = fmaf(d3, d3, acc);
        }
        acc += __shfl_xor(acc, 1);
        acc += __shfl_xor(acc, 2);
        acc += __shfl_xor(acc, 4);
        if (seg == 0) {
            float l2  = sqrtf(acc + 1e-8f);
            float kxv = (t == 31) ? 0.f : expf(-l2);
            kxs[t] = kxv;
            if (quarter == 0)
                out[OUT_KX_OFF + (b * 32 + t) * 32 + q] = kxv;
        }
    }
    __syncthreads();

    // ---- mix: fm = sum_t kx[t] * Fvc[b,t] ----
    {
        float4 acc = make_float4(0.f, 0.f, 0.f, 0.f);
        const float4* FV = (const float4*)(ws + FVC_OFF) + (size_t)b * 32 * 256;
        for (int i = 0; i < 31; ++i) {
            float kv = kxs[i];
            float4 f = FV[(size_t)i * 256 + tid];
            acc.x = fmaf(kv, f.x, acc.x);
            acc.y = fmaf(kv, f.y, acc.y);
            acc.z = fmaf(kv, f.z, acc.z);
            acc.w = fmaf(kv, f.w, acc.w);
        }
        int s0 = tid * 2;
        *(float4*)(fmP + (s0 >> 4) * 36 + (s0 & 15) * 2) = acc;
    }
    __syncthreads();

    // ---- phase 2: A_v(h) for our 32 h rows (rotated twiddles, 2 chains) ----
    {
        const int hl = tid >> 3;
        const int v0 = (tid & 7) * 2;
        const int h  = quarter * 32 + hl;
        const float2 stp = tw[h];
        float cA = 1.f, sA = 0.f;
        const float2 ib = tw[(112 * h) & 127];
        float cB = ib.x, sB = ib.y;
        float ar0 = 0.f, ai0 = 0.f, ar1 = 0.f, ai1 = 0.f;
        #pragma unroll 4
        for (int j = 0; j < 16; ++j) {
            float4 fa = *(const float4*)(fmP + j * 36 + v0 * 2);
            ar0 = fmaf(fa.x, cA, fmaf(-fa.y, sA, ar0));
            ai0 = fmaf(fa.x, sA, fmaf( fa.y, cA, ai0));
            ar1 = fmaf(fa.z, cA, fmaf(-fa.w, sA, ar1));
            ai1 = fmaf(fa.z, sA, fmaf( fa.w, cA, ai1));
            float4 fb = *(const float4*)(fmP + (j + 16) * 36 + v0 * 2);
            ar0 = fmaf(fb.x, cB, fmaf(-fb.y, sB, ar0));
            ai0 = fmaf(fb.x, sB, fmaf( fb.y, cB, ai0));
            ar1 = fmaf(fb.z, cB, fmaf(-fb.w, sB, ar1));
            ai1 = fmaf(fb.z, sB, fmaf( fb.w, cB, ai1));
            float t0 = fmaf(cA, stp.x, -(sA * stp.y));
            float t1 = fmaf(cA, stp.y,  (sA * stp.x));
            cA = t0; sA = t1;
            t0 = fmaf(cB, stp.x, -(sB * stp.y));
            t1 = fmaf(cB, stp.y,  (sB * stp.x));
            cB = t0; sB = t1;
        }
        *(float4*)(Az + hl * 36 + v0 * 2) = make_float4(ar0, ai0, ar1, ai1);
    }

    // per-lane pixel twiddles (w2 = lane; lane+64 via parity trick)
    const int wv   = tid >> 6;
    const int lane = tid & 63;
    float cw[16], sw[16];
    #pragma unroll
    for (int v = 1; v < 16; ++v) {
        float2 t = tw[(v * lane) & 127];
        cw[v] = t.x; sw[v] = t.y;
    }
    __syncthreads();

    // ---- phase 3: 8 rows per wave, 2 pixels per lane per row ----
    for (int lr = 0; lr < 8; ++lr) {
        int l = wv * 8 + lr;
        const float4* az = (const float4*)(Az + l * 36);
        float4 f0 = az[0];
        float base = f0.x;                               // v=0 (real part)
        float accO = f0.z * cw[1] - f0.w * sw[1];        // v=1
        float accE = 0.f;
        #pragma unroll
        for (int t2 = 1; t2 < 8; ++t2) {
            float4 f = az[t2];
            accE = fmaf(f.x, cw[2 * t2],     fmaf(-f.y, sw[2 * t2],     accE));
            accO = fmaf(f.z, cw[2 * t2 + 1], fmaf(-f.w, sw[2 * t2 + 1], accO));
        }
        float pA = base + 2.f * (accE + accO);
        float pB = base + 2.f * (accE - accO);
        int r = quarter * 32 + l;
        out[obase + (size_t)(128 + r) * 128 + lane]      = pA * OUT_SCALE;
        out[obase + (size_t)(128 + r) * 128 + lane + 64] = pB * OUT_SCALE;
    }
}

extern "C" void kernel_launch(void* const* d_in, const int* in_sizes, int n_in,
                              void* d_out, int out_size, void* d_ws, size_t ws_size,
                              hipStream_t stream)
{
    (void)in_sizes; (void)n_in; (void)out_size; (void)ws_size;
    const float* z    = (const float*)d_in[0];
    const float* qw1r = (const float*)d_in[1];
    const float* qw1i = (const float*)d_in[2];
    const float* qw2r = (const float*)d_in[3];
    const float* qw2i = (const float*)d_in[4];
    const float* kw1r = (const float*)d_in[5];
    const float* kw1i = (const float*)d_in[6];
    const float* kw2r = (const float*)d_in[7];
    const float* kw2i = (const float*)d_in[8];
    const float* icl  = (const float*)d_in[9];
    const float* ker  = (const float*)d_in[10];
    float* ws  = (float*)d_ws;
    float* out = (float*)d_out;

    hipLaunchKernelGGL(dft_modes_kernel, dim3(256), dim3(512), 0, stream,
                       z, qw1r, qw1i, qw2r, qw2i, kw1r, kw1i, kw2r, kw2i,
                       icl, ker, ws, out);
    hipLaunchKernelGGL(dist_mix_inv_kernel, dim3(512), dim3(256), 0, stream, ws, out);
}